// Round 2
// baseline (465.221 us; speedup 1.0000x reference)
//
#include <hip/hip_runtime.h>
#include <hip/hip_bf16.h>

// ---------------------------------------------------------------------------
// MultiHeadAttention: x[2,2048,2048] f32, W_qkv[6144,2048], W_out[2048,2048]
// out = MHA(x) in fp32. Internally bf16 MFMA with fp32 accumulation.
// ---------------------------------------------------------------------------

typedef short bf16x8 __attribute__((ext_vector_type(8)));
typedef float f32x4  __attribute__((ext_vector_type(4)));

#define MFMA(a, b, c) __builtin_amdgcn_mfma_f32_16x16x32_bf16((a), (b), (c), 0, 0, 0)

#define GLDS16(gp, lp) __builtin_amdgcn_global_load_lds(                        \
    (const __attribute__((address_space(1))) void*)(gp),                        \
    (__attribute__((address_space(3))) void*)(lp), 16, 0, 0)

static __device__ __forceinline__ unsigned short f2bf(float f) {
    __hip_bfloat16 h = __float2bfloat16(f);
    return *reinterpret_cast<unsigned short*>(&h);
}

// ---------------- fp32 -> bf16 convert (vectorized) ------------------------
__global__ __launch_bounds__(256) void cvt_f32_bf16(const float* __restrict__ in,
                                                    unsigned short* __restrict__ out,
                                                    int n4) {
    int i = blockIdx.x * 256 + threadIdx.x;
    if (i < n4) {
        float4 v = reinterpret_cast<const float4*>(in)[i];
        ushort4 o;
        o.x = f2bf(v.x); o.y = f2bf(v.y); o.z = f2bf(v.z); o.w = f2bf(v.w);
        reinterpret_cast<ushort4*>(out)[i] = o;
    }
}

// ---------------- GEMM: C[M,N] = A[M,K] * W[N,K]^T (both K-contiguous) ------
// m97 structure: 128x128 tile, BK=32, 4 waves (2x2 of 64x64), global_load_lds.
template <bool BF16OUT>
__global__ __launch_bounds__(256) void gemm_bt(const unsigned short* __restrict__ A,
                                               const unsigned short* __restrict__ W,
                                               void* __restrict__ Cout,
                                               int M, int N, int K) {
    __shared__ unsigned short As[128 * 32];
    __shared__ unsigned short Bs[128 * 32];
    const int tid = threadIdx.x;
    const int w = tid >> 6, lane = tid & 63;
    const int fr = lane & 15, fq = lane >> 4;
    const int m0 = blockIdx.y * 128, n0 = blockIdx.x * 128;
    const int wr = w >> 1, wc = w & 1;

    f32x4 acc[4][4];
#pragma unroll
    for (int a = 0; a < 4; a++)
#pragma unroll
        for (int b = 0; b < 4; b++) acc[a][b] = f32x4{0.f, 0.f, 0.f, 0.f};

    const int srow = w * 16 + (lane >> 2);   // staging row within 64-row chunk
    const int scol = (lane & 3) * 8;         // staging col (8 bf16 = 16B)

    for (int kt = 0; kt < K; kt += 32) {
        __syncthreads();
#pragma unroll
        for (int it = 0; it < 2; ++it) {
            const unsigned short* ga = A + (size_t)(m0 + it * 64 + srow) * K + kt + scol;
            unsigned short* la = As + (it * 64 + w * 16) * 32;   // wave-uniform base
            GLDS16(ga, la);
            const unsigned short* gb = W + (size_t)(n0 + it * 64 + srow) * K + kt + scol;
            unsigned short* lb = Bs + (it * 64 + w * 16) * 32;
            GLDS16(gb, lb);
        }
        asm volatile("s_waitcnt vmcnt(0)" ::: "memory");
        __syncthreads();

        bf16x8 af[4], bfr[4];
#pragma unroll
        for (int mi = 0; mi < 4; mi++)
            af[mi] = *reinterpret_cast<const bf16x8*>(As + (wr * 64 + mi * 16 + fr) * 32 + fq * 8);
#pragma unroll
        for (int ni = 0; ni < 4; ni++)
            bfr[ni] = *reinterpret_cast<const bf16x8*>(Bs + (wc * 64 + ni * 16 + fr) * 32 + fq * 8);
#pragma unroll
        for (int mi = 0; mi < 4; mi++)
#pragma unroll
            for (int ni = 0; ni < 4; ni++)
                acc[mi][ni] = MFMA(af[mi], bfr[ni], acc[mi][ni]);
    }

    // epilogue: C/D layout col=lane&15, row=(lane>>4)*4+reg  [verified m89/m91]
#pragma unroll
    for (int mi = 0; mi < 4; mi++) {
#pragma unroll
        for (int i = 0; i < 4; i++) {
            const int row = m0 + wr * 64 + mi * 16 + fq * 4 + i;
            const size_t base = (size_t)row * N + n0 + wc * 64 + fr;
#pragma unroll
            for (int ni = 0; ni < 4; ni++) {
                if (BF16OUT)
                    ((unsigned short*)Cout)[base + ni * 16] = f2bf(acc[mi][ni][i]);
                else
                    ((float*)Cout)[base + ni * 16] = acc[mi][ni][i];
            }
        }
    }
}

// ---------------- V transpose: qkv V-part [4096][2048] -> vT[2][2048][2048] --
// vT[(b*2048 + h*128+dk)*2048 + s] = qkv[(b*2048+s)*6144 + 4096 + h*128+dk]
__global__ __launch_bounds__(256) void transpose_v(const unsigned short* __restrict__ qkv,
                                                   unsigned short* __restrict__ vT) {
    __shared__ unsigned short t[32][33];
    const int b = blockIdx.z, ts = blockIdx.x, tu = blockIdx.y;
    const int i = threadIdx.x >> 5, j = threadIdx.x & 31;
#pragma unroll
    for (int ii = 0; ii < 4; ++ii) {
        const int row = i + ii * 8;  // s-local
        t[row][j] = qkv[(size_t)(b * 2048 + ts * 32 + row) * 6144 + 4096 + tu * 32 + j];
    }
    __syncthreads();
#pragma unroll
    for (int ii = 0; ii < 4; ++ii) {
        const int row = i + ii * 8;  // u-local
        vT[(size_t)(b * 2048 + tu * 32 + row) * 2048 + ts * 32 + j] = t[j][row];
    }
}

// ---------------- Flash attention, causal, wave-independent -----------------
// Each wave owns 16 q-rows of one (b,h). KVBLK=32. Cross-iteration K prefetch
// (register double-buffer, static names), V loaded at compute top / used at
// bottom. Block's 4 waves share one (b,h) on 4 consecutive q-tiles (L1 reuse);
// bh低3bit == blockIdx%8 pins 4 heads per XCD L2.
#define SM_SCALE 0.08838834764831845f

#define LOADK(kb_, kf_) do {                                                    \
    const int k0_ = (kb_) * 32;                                                 \
    _Pragma("unroll")                                                           \
    for (int t2 = 0; t2 < 2; t2++) {                                            \
        const unsigned short* kr_ = Kb + (size_t)(k0_ + t2 * 16 + fr) * 6144 + fq * 8; \
        _Pragma("unroll")                                                       \
        for (int c = 0; c < 4; c++) (kf_)[t2][c] = *reinterpret_cast<const bf16x8*>(kr_ + c * 32); \
    }                                                                           \
} while (0)

#define COMPUTE(kb_, kf_) do {                                                  \
    const int k0_ = (kb_) * 32;                                                 \
    /* V loads issued first: in flight across QK^T + softmax */                 \
    bf16x8 vf_[8];                                                              \
    _Pragma("unroll")                                                           \
    for (int f = 0; f < 8; f++)                                                 \
        vf_[f] = *reinterpret_cast<const bf16x8*>(Vb + (size_t)(f * 16 + fr) * 2048 + k0_ + fq * 8); \
    f32x4 s0 = f32x4{0.f, 0.f, 0.f, 0.f}, s1 = f32x4{0.f, 0.f, 0.f, 0.f};       \
    __builtin_amdgcn_s_setprio(1);                                              \
    _Pragma("unroll")                                                           \
    for (int c = 0; c < 4; c++) {                                               \
        s0 = MFMA(qf[c], (kf_)[0][c], s0);                                      \
        s1 = MFMA(qf[c], (kf_)[1][c], s1);                                      \
    }                                                                           \
    __builtin_amdgcn_s_setprio(0);                                              \
    const bool last_ = (kb_) == nb - 1;                                         \
    float a0_[4], a1_[4], mx_[4];                                               \
    _Pragma("unroll")                                                           \
    for (int i = 0; i < 4; i++) {                                               \
        const int qrow_ = q0 + fq * 4 + i;                                      \
        a0_[i] = s0[i] * SM_SCALE; a1_[i] = s1[i] * SM_SCALE;                   \
        if (last_) {                                                            \
            if (k0_ + fr > qrow_) a0_[i] = -__builtin_inff();                   \
            if (k0_ + 16 + fr > qrow_) a1_[i] = -__builtin_inff();              \
        }                                                                       \
        mx_[i] = fmaxf(a0_[i], a1_[i]);                                         \
    }                                                                           \
    /* stage-major: 4 independent shfl chains interleaved */                    \
    _Pragma("unroll")                                                           \
    for (int st = 1; st <= 8; st <<= 1) {                                       \
        _Pragma("unroll")                                                       \
        for (int i = 0; i < 4; i++) mx_[i] = fmaxf(mx_[i], __shfl_xor(mx_[i], st, 64)); \
    }                                                                           \
    float p0_[4], p1_[4], su_[4];                                               \
    _Pragma("unroll")                                                           \
    for (int i = 0; i < 4; i++) {                                               \
        const float mn_ = fmaxf(m_r[i], mx_[i]);                                \
        const float corr_ = __expf(m_r[i] - mn_);                               \
        p0_[i] = __expf(a0_[i] - mn_);                                          \
        p1_[i] = __expf(a1_[i] - mn_);                                          \
        su_[i] = p0_[i] + p1_[i];                                               \
        m_r[i] = mn_; l_r[i] *= corr_;                                          \
        _Pragma("unroll")                                                       \
        for (int f = 0; f < 8; f++) acc[f][i] *= corr_;                         \
    }                                                                           \
    _Pragma("unroll")                                                           \
    for (int st = 1; st <= 8; st <<= 1) {                                       \
        _Pragma("unroll")                                                       \
        for (int i = 0; i < 4; i++) su_[i] += __shfl_xor(su_[i], st, 64);       \
    }                                                                           \
    _Pragma("unroll")                                                           \
    for (int i = 0; i < 4; i++) {                                               \
        l_r[i] += su_[i];                                                       \
        Pw[(fq * 4 + i) * 40 + fr] = f2bf(p0_[i]);                              \
        Pw[(fq * 4 + i) * 40 + 16 + fr] = f2bf(p1_[i]);                         \
    }                                                                           \
    bf16x8 pa_ = *reinterpret_cast<const bf16x8*>(Pw + fr * 40 + fq * 8);       \
    __builtin_amdgcn_s_setprio(1);                                              \
    _Pragma("unroll")                                                           \
    for (int f = 0; f < 8; f++) acc[f] = MFMA(pa_, vf_[f], acc[f]);             \
    __builtin_amdgcn_s_setprio(0);                                              \
} while (0)

__global__ __launch_bounds__(256, 2) void attn_fwd(const unsigned short* __restrict__ qkv,
                                                   const unsigned short* __restrict__ vT,
                                                   unsigned short* __restrict__ ao) {
    __shared__ __align__(16) unsigned short Ps[4][16 * 40];
    const int tid = threadIdx.x;
    const int w = tid >> 6, lane = tid & 63;
    const int fr = lane & 15, fq = lane >> 4;
    // Block mapping: all 4 waves share one (b,h); 4 consecutive q-tiles.
    // bh & 7 == blockIdx & 7  =>  each XCD's L2 sees only 4 heads (~4MB K+V).
    const int t = blockIdx.x;           // 0..1023
    const int j = t >> 3;               // 0..127
    const int bh = (t & 7) | ((j & 3) << 3);
    const int g = j >> 2;               // 0..31
    const int qi = (31 - g) * 4 + w;    // heavy (large q0) first
    const int b = bh >> 4, h = bh & 15;
    const int q0 = qi * 16;

    const unsigned short* Qb = qkv + (size_t)b * 2048 * 6144 + h * 128;
    const unsigned short* Kb = qkv + (size_t)b * 2048 * 6144 + (16 + h) * 128;
    const unsigned short* Vb = vT + (size_t)bh * 128 * 2048;

    bf16x8 qf[4];
    {
        const unsigned short* qr = Qb + (size_t)(q0 + fr) * 6144 + fq * 8;
#pragma unroll
        for (int c = 0; c < 4; c++) qf[c] = *reinterpret_cast<const bf16x8*>(qr + c * 32);
    }

    f32x4 acc[8];
#pragma unroll
    for (int f = 0; f < 8; f++) acc[f] = f32x4{0.f, 0.f, 0.f, 0.f};
    float m_r[4], l_r[4];
#pragma unroll
    for (int i = 0; i < 4; i++) { m_r[i] = -__builtin_inff(); l_r[i] = 0.f; }

    const int nb = (q0 >> 5) + 1;
    unsigned short* Pw = &Ps[w][0];

    // K register double-buffer with static names (rule #20): A/B alternation.
    bf16x8 kfA[2][4], kfB[2][4];
    LOADK(0, kfA);
    int kb = 0;
    for (;;) {
        if (kb + 1 < nb) LOADK(kb + 1, kfB);
        COMPUTE(kb, kfA);
        ++kb; if (kb >= nb) break;
        if (kb + 1 < nb) LOADK(kb + 1, kfA);
        COMPUTE(kb, kfB);
        ++kb; if (kb >= nb) break;
    }

    // epilogue: normalize and store bf16 [4096][2048]
#pragma unroll
    for (int f = 0; f < 8; f++) {
#pragma unroll
        for (int i = 0; i < 4; i++) {
            const int qrow = q0 + fq * 4 + i;
            const float o = acc[f][i] / l_r[i];
            ao[(size_t)(b * 2048 + qrow) * 2048 + h * 128 + f * 16 + fr] = f2bf(o);
        }
    }
}

// ---------------------------------------------------------------------------
extern "C" void kernel_launch(void* const* d_in, const int* in_sizes, int n_in,
                              void* d_out, int out_size, void* d_ws, size_t ws_size,
                              hipStream_t stream) {
    const float* x    = (const float*)d_in[0];
    const float* Wqkv = (const float*)d_in[1];
    const float* Wout = (const float*)d_in[2];
    float* out = (float*)d_out;

    // Workspace layout (96 MB), regions reused across phases:
    //   [0,16M):   xb (bf16 x), later reused as attnb
    //   [16M,40M): wqkvb (24M), later reused as vT (16M)
    //   [40M,48M): woutb
    //   [48M,96M): qkvb (bf16 [4096][6144])
    char* ws = (char*)d_ws;
    unsigned short* xb    = (unsigned short*)(ws);
    unsigned short* wqkvb = (unsigned short*)(ws + (size_t)(16 << 20));
    unsigned short* woutb = (unsigned short*)(ws + (size_t)(40 << 20));
    unsigned short* qkvb  = (unsigned short*)(ws + (size_t)(48 << 20));
    unsigned short* vTb   = (unsigned short*)(ws + (size_t)(16 << 20)); // over wqkvb
    unsigned short* attnb = (unsigned short*)(ws);                      // over xb

    cvt_f32_bf16<<<8192, 256, 0, stream>>>(x, xb, 2097152);
    cvt_f32_bf16<<<12288, 256, 0, stream>>>(Wqkv, wqkvb, 3145728);
    cvt_f32_bf16<<<4096, 256, 0, stream>>>(Wout, woutb, 1048576);

    // qkv = x @ W_qkv^T : M=4096, N=6144, K=2048, bf16 out
    gemm_bt<true><<<dim3(48, 32), 256, 0, stream>>>(xb, wqkvb, qkvb, 4096, 6144, 2048);

    // vT[b][h*128+dk][s] = V[b][s][h*128+dk]  (wqkvb dead after the GEMM)
    transpose_v<<<dim3(64, 64, 2), 256, 0, stream>>>(qkvb, vTb);

    // causal flash attention -> attnb (bf16 [4096][2048])  (xb dead now)
    attn_fwd<<<1024, 256, 0, stream>>>(qkvb, vTb, attnb);

    // out = attnb @ W_out^T : M=4096, N=2048, K=2048, fp32 out
    gemm_bt<false><<<dim3(16, 32), 256, 0, stream>>>(attnb, woutb, out, 4096, 2048, 2048);
}

// Round 3
// 331.863 us; speedup vs baseline: 1.4018x; 1.4018x over previous
//
#include <hip/hip_runtime.h>
#include <hip/hip_bf16.h>

// ---------------------------------------------------------------------------
// MultiHeadAttention: x[2,2048,2048] f32, W_qkv[6144,2048], W_out[2048,2048]
// out = MHA(x) in fp32. Internally bf16 MFMA with fp32 accumulation.
// ---------------------------------------------------------------------------

typedef short bf16x8 __attribute__((ext_vector_type(8)));
typedef float f32x4  __attribute__((ext_vector_type(4)));

#define MFMA(a, b, c) __builtin_amdgcn_mfma_f32_16x16x32_bf16((a), (b), (c), 0, 0, 0)

#define GLDS16(gp, lp) __builtin_amdgcn_global_load_lds(                        \
    (const __attribute__((address_space(1))) void*)(gp),                        \
    (__attribute__((address_space(3))) void*)(lp), 16, 0, 0)

static __device__ __forceinline__ unsigned short f2bf(float f) {
    __hip_bfloat16 h = __float2bfloat16(f);
    return *reinterpret_cast<unsigned short*>(&h);
}

// ---------------- fp32 -> bf16 convert (vectorized) ------------------------
__global__ __launch_bounds__(256) void cvt_f32_bf16(const float* __restrict__ in,
                                                    unsigned short* __restrict__ out,
                                                    int n4) {
    int i = blockIdx.x * 256 + threadIdx.x;
    if (i < n4) {
        float4 v = reinterpret_cast<const float4*>(in)[i];
        ushort4 o;
        o.x = f2bf(v.x); o.y = f2bf(v.y); o.z = f2bf(v.z); o.w = f2bf(v.w);
        reinterpret_cast<ushort4*>(out)[i] = o;
    }
}

// ---------------- GEMM: C[M,N] = A[M,K] * W[N,K]^T (both K-contiguous) ------
// m97 structure: 128x128 tile, BK=32, 4 waves (2x2 of 64x64), global_load_lds.
template <bool BF16OUT>
__global__ __launch_bounds__(256) void gemm_bt(const unsigned short* __restrict__ A,
                                               const unsigned short* __restrict__ W,
                                               void* __restrict__ Cout,
                                               int M, int N, int K) {
    __shared__ unsigned short As[128 * 32];
    __shared__ unsigned short Bs[128 * 32];
    const int tid = threadIdx.x;
    const int w = tid >> 6, lane = tid & 63;
    const int fr = lane & 15, fq = lane >> 4;
    const int m0 = blockIdx.y * 128, n0 = blockIdx.x * 128;
    const int wr = w >> 1, wc = w & 1;

    f32x4 acc[4][4];
#pragma unroll
    for (int a = 0; a < 4; a++)
#pragma unroll
        for (int b = 0; b < 4; b++) acc[a][b] = f32x4{0.f, 0.f, 0.f, 0.f};

    const int srow = w * 16 + (lane >> 2);   // staging row within 64-row chunk
    const int scol = (lane & 3) * 8;         // staging col (8 bf16 = 16B)

    for (int kt = 0; kt < K; kt += 32) {
        __syncthreads();
#pragma unroll
        for (int it = 0; it < 2; ++it) {
            const unsigned short* ga = A + (size_t)(m0 + it * 64 + srow) * K + kt + scol;
            unsigned short* la = As + (it * 64 + w * 16) * 32;   // wave-uniform base
            GLDS16(ga, la);
            const unsigned short* gb = W + (size_t)(n0 + it * 64 + srow) * K + kt + scol;
            unsigned short* lb = Bs + (it * 64 + w * 16) * 32;
            GLDS16(gb, lb);
        }
        asm volatile("s_waitcnt vmcnt(0)" ::: "memory");
        __syncthreads();

        bf16x8 af[4], bfr[4];
#pragma unroll
        for (int mi = 0; mi < 4; mi++)
            af[mi] = *reinterpret_cast<const bf16x8*>(As + (wr * 64 + mi * 16 + fr) * 32 + fq * 8);
#pragma unroll
        for (int ni = 0; ni < 4; ni++)
            bfr[ni] = *reinterpret_cast<const bf16x8*>(Bs + (wc * 64 + ni * 16 + fr) * 32 + fq * 8);
#pragma unroll
        for (int mi = 0; mi < 4; mi++)
#pragma unroll
            for (int ni = 0; ni < 4; ni++)
                acc[mi][ni] = MFMA(af[mi], bfr[ni], acc[mi][ni]);
    }

    // epilogue: C/D layout col=lane&15, row=(lane>>4)*4+reg  [verified m89/m91]
#pragma unroll
    for (int mi = 0; mi < 4; mi++) {
#pragma unroll
        for (int i = 0; i < 4; i++) {
            const int row = m0 + wr * 64 + mi * 16 + fq * 4 + i;
            const size_t base = (size_t)row * N + n0 + wc * 64 + fr;
#pragma unroll
            for (int ni = 0; ni < 4; ni++) {
                if (BF16OUT)
                    ((unsigned short*)Cout)[base + ni * 16] = f2bf(acc[mi][ni][i]);
                else
                    ((float*)Cout)[base + ni * 16] = acc[mi][ni][i];
            }
        }
    }
}

// ---------------- V transpose: qkv V-part [4096][2048] -> vT[2][2048][2048] --
// vT[(b*2048 + h*128+dk)*2048 + s] = qkv[(b*2048+s)*6144 + 4096 + h*128+dk]
__global__ __launch_bounds__(256) void transpose_v(const unsigned short* __restrict__ qkv,
                                                   unsigned short* __restrict__ vT) {
    __shared__ unsigned short t[32][33];
    const int b = blockIdx.z, ts = blockIdx.x, tu = blockIdx.y;
    const int i = threadIdx.x >> 5, j = threadIdx.x & 31;
#pragma unroll
    for (int ii = 0; ii < 4; ++ii) {
        const int row = i + ii * 8;  // s-local
        t[row][j] = qkv[(size_t)(b * 2048 + ts * 32 + row) * 6144 + 4096 + tu * 32 + j];
    }
    __syncthreads();
#pragma unroll
    for (int ii = 0; ii < 4; ++ii) {
        const int row = i + ii * 8;  // u-local
        vT[(size_t)(b * 2048 + tu * 32 + row) * 2048 + ts * 32 + j] = t[j][row];
    }
}

// ---------------- Flash attention, causal, block-cooperative ----------------
// Block = one (b,h), 64-row q-supertile, 4 waves x 16 q-rows. Per kv-iter the
// block stages K[32][128] and Vt[128][32] into double-buffered LDS via
// global_load_lds (coalesced, pre-swizzled source, XOR-swizzled reads).
// K swizzle: byte ^= ((row&7)<<4)   (row stride 256B)  [m214-verified]
// V swizzle: byte ^= (((row>>1)&3)<<4) (row stride 64B, 2-way residual = free)
#define SM_SCALE 0.08838834764831845f

__global__ __launch_bounds__(256, 2) void attn_fwd(const unsigned short* __restrict__ qkv,
                                                   const unsigned short* __restrict__ vT,
                                                   unsigned short* __restrict__ ao) {
    __shared__ __align__(16) char Kt[2][8192];
    __shared__ __align__(16) char Vt[2][8192];
    __shared__ __align__(16) unsigned short Ps[4][16 * 40];
    const int tid = threadIdx.x;
    const int w = tid >> 6, lane = tid & 63;
    const int fr = lane & 15, fq = lane >> 4;
    // bh = blockIdx&31 -> bh%8 == XCD id (round-robin): 4 heads per XCD L2.
    // g (supertile) heavy-first so long waves start early.
    const int t = blockIdx.x;           // 0..1023
    const int bh = t & 31;
    const int g = 31 - (t >> 5);        // 0..31
    const int b = bh >> 4, h = bh & 15;
    const int q0 = g * 64 + w * 16;     // this wave's 16 q-rows
    const int nb = 2 * g + 2;           // kv blocks for the supertile

    const unsigned short* Qb = qkv + (size_t)b * 2048 * 6144 + h * 128;
    const unsigned short* Kb = qkv + (size_t)b * 2048 * 6144 + (16 + h) * 128;
    const unsigned short* Vb = vT + (size_t)bh * 128 * 2048;

    bf16x8 qf[4];
    {
        const unsigned short* qr = Qb + (size_t)(q0 + fr) * 6144 + fq * 8;
#pragma unroll
        for (int c = 0; c < 4; c++) qf[c] = *reinterpret_cast<const bf16x8*>(qr + c * 32);
    }

    f32x4 acc[8];
#pragma unroll
    for (int f = 0; f < 8; f++) acc[f] = f32x4{0.f, 0.f, 0.f, 0.f};
    float m_r[4], l_r[4];
#pragma unroll
    for (int i = 0; i < 4; i++) { m_r[i] = -__builtin_inff(); l_r[i] = 0.f; }

    unsigned short* Pw = &Ps[w][0];

    // ---- staging: waves 0,1 stage K (8 x 1KB), waves 2,3 stage Vt (8 x 1KB).
    // K instr i: LDS rows 4i..4i+3 (256B each); lane l -> row 4i+(l>>4),
    //   source col elem = (((l&15)*16) ^ ((r&7)<<4)) / 2.
    // V instr i: LDS rows 16i..16i+15 (64B each); lane l -> row 16i+(l>>2),
    //   source col elem = ((l&3) ^ ((l>>3)&3)) * 8.
    auto stage = [&](int kbs, int bufi) {
        const int k0s = kbs * 32;
        if (w < 2) {
#pragma unroll
            for (int q = 0; q < 4; ++q) {
                const int i = w * 4 + q;
                const int r = 4 * i + (lane >> 4);
                const int ce = ((((lane & 15) * 16) ^ ((r & 7) << 4))) >> 1;
                const unsigned short* gp = Kb + (size_t)(k0s + r) * 6144 + ce;
                GLDS16(gp, &Kt[bufi][i * 1024]);
            }
        } else {
#pragma unroll
            for (int q = 0; q < 4; ++q) {
                const int i = (w - 2) * 4 + q;
                const int r = 16 * i + (lane >> 2);
                const int ce = ((lane & 3) ^ ((lane >> 3) & 3)) * 8;
                const unsigned short* gp = Vb + (size_t)r * 2048 + k0s + ce;
                GLDS16(gp, &Vt[bufi][i * 1024]);
            }
        }
    };

    int cur = 0;
    stage(0, 0);
    __syncthreads();   // compiler drains vmcnt before s_barrier

    for (int kb = 0; kb < nb; ++kb) {
        if (kb + 1 < nb) stage(kb + 1, cur ^ 1);
        const int k0 = kb * 32;
        if (k0 <= q0 + 15) {   // wave-uniform: skip fully-masked tiles
            const char* Kl = &Kt[cur][0];
            const char* Vl = &Vt[cur][0];
            bf16x8 kf[2][4];
#pragma unroll
            for (int t2 = 0; t2 < 2; t2++)
#pragma unroll
                for (int c = 0; c < 4; c++)
                    kf[t2][c] = *reinterpret_cast<const bf16x8*>(
                        Kl + (t2 * 16 + fr) * 256 + ((c * 64 + fq * 16) ^ ((fr & 7) << 4)));
            f32x4 s0 = f32x4{0.f, 0.f, 0.f, 0.f}, s1 = f32x4{0.f, 0.f, 0.f, 0.f};
            __builtin_amdgcn_s_setprio(1);
#pragma unroll
            for (int c = 0; c < 4; c++) {
                s0 = MFMA(qf[c], kf[0][c], s0);
                s1 = MFMA(qf[c], kf[1][c], s1);
            }
            __builtin_amdgcn_s_setprio(0);
            // V fragments (issued early; consumed after softmax)
            bf16x8 vf[8];
#pragma unroll
            for (int f = 0; f < 8; f++)
                vf[f] = *reinterpret_cast<const bf16x8*>(
                    Vl + (f * 16 + fr) * 64 + ((fq * 16) ^ (((fr >> 1) & 3) << 4)));

            const bool msk = (k0 + 31 > q0);
            float a0_[4], a1_[4], mx_[4];
#pragma unroll
            for (int i = 0; i < 4; i++) {
                const int qrow = q0 + fq * 4 + i;
                a0_[i] = s0[i] * SM_SCALE; a1_[i] = s1[i] * SM_SCALE;
                if (msk) {
                    if (k0 + fr > qrow) a0_[i] = -__builtin_inff();
                    if (k0 + 16 + fr > qrow) a1_[i] = -__builtin_inff();
                }
                mx_[i] = fmaxf(a0_[i], a1_[i]);
            }
#pragma unroll
            for (int st = 1; st <= 8; st <<= 1) {
#pragma unroll
                for (int i = 0; i < 4; i++) mx_[i] = fmaxf(mx_[i], __shfl_xor(mx_[i], st, 64));
            }
            float p0_[4], p1_[4], su_[4];
#pragma unroll
            for (int i = 0; i < 4; i++) {
                const float mn = fmaxf(m_r[i], mx_[i]);
                const float corr = __expf(m_r[i] - mn);
                p0_[i] = __expf(a0_[i] - mn);
                p1_[i] = __expf(a1_[i] - mn);
                su_[i] = p0_[i] + p1_[i];
                m_r[i] = mn; l_r[i] *= corr;
#pragma unroll
                for (int f = 0; f < 8; f++) acc[f][i] *= corr;
            }
#pragma unroll
            for (int st = 1; st <= 8; st <<= 1) {
#pragma unroll
                for (int i = 0; i < 4; i++) su_[i] += __shfl_xor(su_[i], st, 64);
            }
#pragma unroll
            for (int i = 0; i < 4; i++) {
                l_r[i] += su_[i];
                Pw[(fq * 4 + i) * 40 + fr] = f2bf(p0_[i]);
                Pw[(fq * 4 + i) * 40 + 16 + fr] = f2bf(p1_[i]);
            }
            bf16x8 pa = *reinterpret_cast<const bf16x8*>(Pw + fr * 40 + fq * 8);
            __builtin_amdgcn_s_setprio(1);
#pragma unroll
            for (int f = 0; f < 8; f++) acc[f] = MFMA(pa, vf[f], acc[f]);
            __builtin_amdgcn_s_setprio(0);
        }
        __syncthreads();
        cur ^= 1;
    }

    // epilogue: normalize and store bf16 [4096][2048]
#pragma unroll
    for (int f = 0; f < 8; f++) {
#pragma unroll
        for (int i = 0; i < 4; i++) {
            const int qrow = q0 + fq * 4 + i;
            const float o = acc[f][i] / l_r[i];
            ao[(size_t)(b * 2048 + qrow) * 2048 + h * 128 + f * 16 + fr] = f2bf(o);
        }
    }
}

// ---------------------------------------------------------------------------
extern "C" void kernel_launch(void* const* d_in, const int* in_sizes, int n_in,
                              void* d_out, int out_size, void* d_ws, size_t ws_size,
                              hipStream_t stream) {
    const float* x    = (const float*)d_in[0];
    const float* Wqkv = (const float*)d_in[1];
    const float* Wout = (const float*)d_in[2];
    float* out = (float*)d_out;

    // Workspace layout (96 MB), regions reused across phases:
    //   [0,16M):   xb (bf16 x), later reused as attnb
    //   [16M,40M): wqkvb (24M), later reused as vT (16M)
    //   [40M,48M): woutb
    //   [48M,96M): qkvb (bf16 [4096][6144])
    char* ws = (char*)d_ws;
    unsigned short* xb    = (unsigned short*)(ws);
    unsigned short* wqkvb = (unsigned short*)(ws + (size_t)(16 << 20));
    unsigned short* woutb = (unsigned short*)(ws + (size_t)(40 << 20));
    unsigned short* qkvb  = (unsigned short*)(ws + (size_t)(48 << 20));
    unsigned short* vTb   = (unsigned short*)(ws + (size_t)(16 << 20)); // over wqkvb
    unsigned short* attnb = (unsigned short*)(ws);                      // over xb

    cvt_f32_bf16<<<8192, 256, 0, stream>>>(x, xb, 2097152);
    cvt_f32_bf16<<<12288, 256, 0, stream>>>(Wqkv, wqkvb, 3145728);
    cvt_f32_bf16<<<4096, 256, 0, stream>>>(Wout, woutb, 1048576);

    // qkv = x @ W_qkv^T : M=4096, N=6144, K=2048, bf16 out
    gemm_bt<true><<<dim3(48, 32), 256, 0, stream>>>(xb, wqkvb, qkvb, 4096, 6144, 2048);

    // vT[b][h*128+dk][s] = V[b][s][h*128+dk]  (wqkvb dead after the GEMM)
    transpose_v<<<dim3(64, 64, 2), 256, 0, stream>>>(qkvb, vTb);

    // causal flash attention -> attnb (bf16 [4096][2048])  (xb dead now)
    attn_fwd<<<1024, 256, 0, stream>>>(qkvb, vTb, attnb);

    // out = attnb @ W_out^T : M=4096, N=2048, K=2048, fp32 out
    gemm_bt<false><<<dim3(16, 32), 256, 0, stream>>>(attnb, woutb, out, 4096, 2048, 2048);
}